// Round 17
// baseline (907.348 us; speedup 1.0000x reference)
//
#include <hip/hip_runtime.h>
#include <math.h>

#define Bn 128
#define Tn 512
#define Dn 32
#define Hn 128
#define Gn 512   // 4*H
#define Ln 3

// LDS-only barrier: does NOT drain vmcnt.
#define BAR_LDS() asm volatile("s_waitcnt lgkmcnt(0)\n\ts_barrier" ::: "memory")

typedef _Float16 h2 __attribute__((ext_vector_type(2)));
typedef _Float16 h4 __attribute__((ext_vector_type(4)));
typedef _Float16 half8 __attribute__((ext_vector_type(8)));   // MFMA A/B frag
typedef float f32x4 __attribute__((ext_vector_type(4)));      // MFMA acc

__device__ __forceinline__ float dot2(h2 a, h2 b, float c) {
    return __builtin_amdgcn_fdot2(a, b, c, false);
}
__device__ __forceinline__ h2 pkh(float a, float b) {
    h2 r; r.x = (_Float16)a; r.y = (_Float16)b; return r;
}
__device__ __forceinline__ float sigm(float x) {
    return __builtin_amdgcn_rcpf(1.f + __expf(-x));
}
__device__ __forceinline__ float tanh_fast(float x) {
    return 1.f - 2.f * __builtin_amdgcn_rcpf(1.f + __expf(2.f * x));
}

// DPP quad_perm butterfly add. 0xB1 = lanes 2i<->2i+1. 0x4E = pair swap.
#define DPPADD(a, CTRL) { \
    int _t = __builtin_amdgcn_update_dpp(0, __builtin_bit_cast(int, a), \
                                         CTRL, 0xF, 0xF, true); \
    a += __builtin_bit_cast(float, _t); }

#define KEEPH(x) asm volatile("" : "+v"(x))
#define LD8H(p) (*(const half8*)(p))
#define H2OF(V, i) (((const h2*)&(V))[i])

#define DECL16(P, R) \
  h2 P##0=pkh((R)[0],(R)[1]),   P##1=pkh((R)[2],(R)[3]),   P##2=pkh((R)[4],(R)[5]),   P##3=pkh((R)[6],(R)[7]),   \
     P##4=pkh((R)[8],(R)[9]),   P##5=pkh((R)[10],(R)[11]), P##6=pkh((R)[12],(R)[13]), P##7=pkh((R)[14],(R)[15]), \
     P##8=pkh((R)[16],(R)[17]), P##9=pkh((R)[18],(R)[19]), P##10=pkh((R)[20],(R)[21]),P##11=pkh((R)[22],(R)[23]),\
     P##12=pkh((R)[24],(R)[25]),P##13=pkh((R)[26],(R)[27]),P##14=pkh((R)[28],(R)[29]),P##15=pkh((R)[30],(R)[31]);
#define KEEP16(P) \
  KEEPH(P##0); KEEPH(P##1); KEEPH(P##2); KEEPH(P##3); KEEPH(P##4); KEEPH(P##5); \
  KEEPH(P##6); KEEPH(P##7); KEEPH(P##8); KEEPH(P##9); KEEPH(P##10); KEEPH(P##11); \
  KEEPH(P##12); KEEPH(P##13); KEEPH(P##14); KEEPH(P##15);

#define EXTRACT16(P, A, B, C, D) \
  h2 P##0 = H2OF(A,0), P##1 = H2OF(A,1), P##2  = H2OF(A,2), P##3  = H2OF(A,3), \
     P##4 = H2OF(B,0), P##5 = H2OF(B,1), P##6  = H2OF(B,2), P##7  = H2OF(B,3), \
     P##8 = H2OF(C,0), P##9 = H2OF(C,1), P##10 = H2OF(C,2), P##11 = H2OF(C,3), \
     P##12= H2OF(D,0), P##13= H2OF(D,1), P##14 = H2OF(D,2), P##15 = H2OF(D,3);

// quad-split dots: hh on hv, ih on pv
#define DOT4V(j) { \
    aI = dot2(hv##j, wi##j, aI);  aF = dot2(hv##j, wf##j, aF); \
    aG = dot2(hv##j, wg##j, aG);  aO = dot2(hv##j, wo##j, aO); }
#define DOT4Y(j) { \
    aI = dot2(pv##j, yi##j, aI);  aF = dot2(pv##j, yf##j, aF); \
    aG = dot2(pv##j, yg##j, aG);  aO = dot2(pv##j, yo##j, aO); }

// ---------------------------------------------------------------------------
// MFMA GEMM with inline dtype conversion (R12, verified). Output quad-
// interleaved pre4[((m>>2)*Gn + g)*4 + (m&3)].
// ---------------------------------------------------------------------------
template<typename TA>
__global__ __launch_bounds__(256) void gemm_pre(
    const TA* __restrict__ A, int K, int rowStrideB, int t0, int tlog,
    const float* __restrict__ W,
    const float* __restrict__ bi, const float* __restrict__ bh,
    _Float16* __restrict__ C)
{
    __shared__ h2 As2[64][20];
    __shared__ h2 Bs2[64][20];
    const int tid  = threadIdx.x;
    const int row0 = blockIdx.x * 64;
    const int col0 = blockIdx.y * 64;
    const int w    = tid >> 6;
    const int lane = tid & 63;
    const int qm   = (w >> 1) * 32;
    const int qn   = (w & 1) * 32;
    const int fm   = lane & 15;
    const int fq   = lane >> 4;
    const int tmask = (1 << tlog) - 1;
    const int lrow = tid >> 2;
    const int lk   = (tid & 3) * 8;

    f32x4 acc00 = {0,0,0,0}, acc01 = {0,0,0,0};
    f32x4 acc10 = {0,0,0,0}, acc11 = {0,0,0,0};

    for (int k0 = 0; k0 < K; k0 += 32) {
        {
            int rg = row0 + lrow;
            int b_idx = rg >> tlog, tt = rg & tmask;
            const TA* ap = A + (size_t)b_idx * rowStrideB +
                           (size_t)(t0 + tt) * K + (k0 + lk);
            if constexpr (sizeof(TA) == 2) {
                *(float4*)&As2[lrow][(tid & 3) * 4] = *(const float4*)ap;
            } else {
                float4 va = *(const float4*)ap;
                float4 vb = *(const float4*)(ap + 4);
                float4 o;
                ((h2*)&o)[0] = pkh(va.x, va.y);
                ((h2*)&o)[1] = pkh(va.z, va.w);
                ((h2*)&o)[2] = pkh(vb.x, vb.y);
                ((h2*)&o)[3] = pkh(vb.z, vb.w);
                *(float4*)&As2[lrow][(tid & 3) * 4] = o;
            }
            const float* wp = W + (size_t)(col0 + lrow) * K + (k0 + lk);
            float4 wa = *(const float4*)wp;
            float4 wb = *(const float4*)(wp + 4);
            float4 ow;
            ((h2*)&ow)[0] = pkh(wa.x, wa.y);
            ((h2*)&ow)[1] = pkh(wa.z, wa.w);
            ((h2*)&ow)[2] = pkh(wb.x, wb.y);
            ((h2*)&ow)[3] = pkh(wb.z, wb.w);
            *(float4*)&Bs2[lrow][(tid & 3) * 4] = ow;
        }
        __syncthreads();
        half8 a0 = *(const half8*)&As2[qm + fm][fq * 4];
        half8 a1 = *(const half8*)&As2[qm + 16 + fm][fq * 4];
        half8 b0 = *(const half8*)&Bs2[qn + fm][fq * 4];
        half8 b1 = *(const half8*)&Bs2[qn + 16 + fm][fq * 4];
        acc00 = __builtin_amdgcn_mfma_f32_16x16x32_f16(a0, b0, acc00, 0, 0, 0);
        acc01 = __builtin_amdgcn_mfma_f32_16x16x32_f16(a0, b1, acc01, 0, 0, 0);
        acc10 = __builtin_amdgcn_mfma_f32_16x16x32_f16(a1, b0, acc10, 0, 0, 0);
        acc11 = __builtin_amdgcn_mfma_f32_16x16x32_f16(a1, b1, acc11, 0, 0, 0);
        __syncthreads();
    }

    const int g0 = col0 + qn + fm;
    const int g1 = g0 + 16;
    const float bb0 = bi[g0] + bh[g0];
    const float bb1 = bi[g1] + bh[g1];
    const int m0 = row0 + qm + fq * 4;
    #pragma unroll
    for (int r = 0; r < 4; r++) {
        int ma = m0 + r, mb = m0 + 16 + r;
        C[((size_t)(ma >> 2) * Gn + g0) * 4 + (ma & 3)] = (_Float16)(acc00[r] + bb0);
        C[((size_t)(ma >> 2) * Gn + g1) * 4 + (ma & 3)] = (_Float16)(acc01[r] + bb1);
        C[((size_t)(mb >> 2) * Gn + g0) * 4 + (mb & 3)] = (_Float16)(acc10[r] + bb0);
        C[((size_t)(mb >> 2) * Gn + g1) * 4 + (mb & 3)] = (_Float16)(acc11[r] + bb1);
    }
}

// ---------------------------------------------------------------------------
// Consumer phase (R16-verified structure): LSTM layer whose ih input is the
// previous layer's h, chunk-staged from global through LDS, gated on a
// producer-published flag; output chunk-flushed and optionally published.
// hb_: h2[2*64] ring; hst_/pL_: _Float16[2*16*128].
// ---------------------------------------------------------------------------
__device__ __forceinline__ void consumer_phase(
    int b, int tid, int lane, int kq4, int u,
    const _Float16* __restrict__ hsin_b,   // [Tn][128] this item's input h
    _Float16* __restrict__ hsout_b,        // [Tn][128] this item's output h
    const float* __restrict__ whh,         // [512][128] recurrent weights
    const float* __restrict__ wih,         // [512][128] input weights
    const float* __restrict__ bih, const float* __restrict__ bhh, // [512]
    int* __restrict__ gate_flags,          // [B] chunks available (acquire)
    int* __restrict__ pub_flags,           // [B] chunks published, or nullptr
    h2* hb_, _Float16* hst_, _Float16* pL_)
{
    const float* rI = whh + (size_t)(0 * Hn + u) * Hn + kq4 * 32;
    const float* rF = whh + (size_t)(1 * Hn + u) * Hn + kq4 * 32;
    const float* rG = whh + (size_t)(2 * Hn + u) * Hn + kq4 * 32;
    const float* rO = whh + (size_t)(3 * Hn + u) * Hn + kq4 * 32;
    DECL16(wi, rI) DECL16(wf, rF) DECL16(wg, rG) DECL16(wo, rO)
    KEEP16(wi) KEEP16(wf) KEEP16(wg) KEEP16(wo)

    const float* yIr = wih + (size_t)(0 * Hn + u) * Hn + kq4 * 32;
    const float* yFr = wih + (size_t)(1 * Hn + u) * Hn + kq4 * 32;
    const float* yGr = wih + (size_t)(2 * Hn + u) * Hn + kq4 * 32;
    const float* yOr = wih + (size_t)(3 * Hn + u) * Hn + kq4 * 32;
    DECL16(yi, yIr) DECL16(yf, yFr) DECL16(yg, yGr) DECL16(yo, yOr)
    KEEP16(yi) KEEP16(yf) KEEP16(yg) KEEP16(yo)

    const float bI1 = bih[0 * Hn + u] + bhh[0 * Hn + u];
    const float bF1 = bih[1 * Hn + u] + bhh[1 * Hn + u];
    const float bG1 = bih[2 * Hn + u] + bhh[2 * Hn + u];
    const float bO1 = bih[3 * Hn + u] + bhh[3 * Hn + u];

    if (tid < Hn / 2) hb_[tid] = pkh(0.f, 0.f);   // hb[0][*] = 0
    float cr = 0.f;

    int avail = 0;
    auto gate = [&](int need) {
        if (avail >= need) return;
        do {
            int a0 = 0;
            if (lane == 0)
                a0 = __hip_atomic_load(gate_flags + b, __ATOMIC_ACQUIRE,
                                       __HIP_MEMORY_SCOPE_AGENT);
            avail = __builtin_amdgcn_readfirstlane(a0);
            if (avail < need) __builtin_amdgcn_s_sleep(8);
        } while (avail < need);
    };

    auto tick = [&](int t) {
        const h2* h1row = hb_ + (t & 1) * (Hn / 2) + kq4 * 16;
        half8 hA = LD8H(h1row);     half8 hB = LD8H(h1row + 4);
        half8 hC = LD8H(h1row + 8); half8 hD = LD8H(h1row + 12);
        EXTRACT16(hv, hA, hB, hC, hD)
        const h2* h0row = (const h2*)(pL_ + ((t >> 4) & 1) * 2048 +
                                      (t & 15) * Hn + kq4 * 32);
        half8 pA = LD8H(h0row);     half8 pB = LD8H(h0row + 4);
        half8 pC = LD8H(h0row + 8); half8 pD = LD8H(h0row + 12);
        EXTRACT16(pv, pA, pB, pC, pD)

        float aI = 0.f, aF = 0.f, aG = 0.f, aO = 0.f;
        DOT4V(0)  DOT4V(1)  DOT4V(2)  DOT4V(3)
        DOT4V(4)  DOT4V(5)  DOT4V(6)  DOT4V(7)
        DOT4V(8)  DOT4V(9)  DOT4V(10) DOT4V(11)
        DOT4V(12) DOT4V(13) DOT4V(14) DOT4V(15)
        DOT4Y(0)  DOT4Y(1)  DOT4Y(2)  DOT4Y(3)
        DOT4Y(4)  DOT4Y(5)  DOT4Y(6)  DOT4Y(7)
        DOT4Y(8)  DOT4Y(9)  DOT4Y(10) DOT4Y(11)
        DOT4Y(12) DOT4Y(13) DOT4Y(14) DOT4Y(15)

        DPPADD(aI, 0xB1) DPPADD(aF, 0xB1) DPPADD(aG, 0xB1) DPPADD(aO, 0xB1)
        DPPADD(aI, 0x4E) DPPADD(aF, 0x4E) DPPADD(aG, 0x4E) DPPADD(aO, 0x4E)

        float iv = sigm(aI + bI1);
        float fv = sigm(aF + bF1);
        float gv = tanh_fast(aG + bG1);
        float ov = sigm(aO + bO1);
        cr = fv * cr + iv * gv;
        float hnew = ov * tanh_fast(cr);
        _Float16 hh = (_Float16)hnew;
        if (kq4 == 0) {
            ((_Float16*)(hb_ + ((t + 1) & 1) * (Hn / 2)))[u] = hh;
            hst_[((t >> 4) & 1) * 2048 + (t & 15) * Hn + u] = hh;
        }
        BAR_LDS();
    };

    // prologue: stage chunk 0
    gate(1);
    if (tid < 256) {
        float4 v = *(const float4*)(hsin_b + tid * 8);
        *(float4*)(pL_ + tid * 8) = v;
    }
    __syncthreads();

    for (int c = 0; c < 32; c++) {
        if (c + 1 < 32) {
            gate(c + 2);
            if (tid < 256) {
                float4 v = *(const float4*)(hsin_b +
                            (size_t)(c + 1) * 16 * Hn + tid * 8);
                *(float4*)(pL_ + ((c + 1) & 1) * 2048 + tid * 8) = v;
            }
        }
        #pragma unroll
        for (int tt = 0; tt < 16; tt++) tick(16 * c + tt);
        // flush out-chunk c (hst_ writes visible after last tick barrier)
        if (tid < 256) {
            float4 v = ((const float4*)(hst_ + (c & 1) * 2048))[tid];
            *(float4*)(hsout_b + (size_t)c * 16 * Hn + tid * 8) = v;
        }
        if (pub_flags != nullptr) {
            asm volatile("s_waitcnt vmcnt(0)" ::: "memory");
            __syncthreads();
            if (tid == 0)
                __hip_atomic_store(pub_flags + b, c + 1, __ATOMIC_RELEASE,
                                   __HIP_MEMORY_SCOPE_AGENT);
        }
    }
}

// ---------------------------------------------------------------------------
// pipe3: full 3-layer wavefront across 256 CUs. grid (128,2) x 512 thr,
// 1 block/CU via 80KB pad -> all blocks co-resident; dep chain L0->L1->L2
// acyclic -> deadlock-free.
//   y=0: producer runs layer 0 (quad-split tick + chunk flush + flags0
//        publish), THEN becomes the layer-2 consumer (gated on flags1).
//   y=1: layer-1 consumer (gated on flags0), publishes flags1 per chunk.
// Consumer structure verbatim from R16 (HW-verified).
// ---------------------------------------------------------------------------
__global__ __launch_bounds__(512)
__attribute__((amdgpu_waves_per_eu(2)))
void pipe3(
    const _Float16* __restrict__ pre0,  // quad-interleaved layer-0 pre
    const float* __restrict__ w_hh,     // [L][512][128] fp32
    const float* __restrict__ wih_rest, // [2][512][128] fp32
    const float* __restrict__ b_ih, const float* __restrict__ b_hh, // [L][512]
    _Float16* __restrict__ hs0,
    _Float16* __restrict__ hs1,
    _Float16* __restrict__ hs2,
    int* __restrict__ flags0, int* __restrict__ flags1)
{
    const int b    = blockIdx.x;
    const int role = blockIdx.y;           // 0: L0 then L2 / 1: L1
    const int tid  = threadIdx.x;
    const int lane = tid & 63;
    const int wv   = tid >> 6;
    const int kq4  = lane & 3;
    const int u    = wv * 16 + (lane >> 2);

    __shared__ h2 hb[2][Hn / 2];
    __shared__ _Float16 hstage[2][16][Hn];
    __shared__ _Float16 pL[2][16][Hn];
    __shared__ float lds_pad[20480];       // 80 KiB occupancy limiter

    if (pre0 == nullptr) {                 // never true; keeps pad live
        lds_pad[tid] = (float)tid;
        __syncthreads();
        ((float*)hs0)[tid] = lds_pad[(tid * 7) & 20479];
    }

    if (role == 0) {
        // =================== PHASE A: produce layer 0 ====================
        const float* whl = w_hh;           // layer 0
        const float* rI = whl + (size_t)(0 * Hn + u) * Hn + kq4 * 32;
        const float* rF = whl + (size_t)(1 * Hn + u) * Hn + kq4 * 32;
        const float* rG = whl + (size_t)(2 * Hn + u) * Hn + kq4 * 32;
        const float* rO = whl + (size_t)(3 * Hn + u) * Hn + kq4 * 32;
        DECL16(wi, rI) DECL16(wf, rF) DECL16(wg, rG) DECL16(wo, rO)
        KEEP16(wi) KEEP16(wf) KEEP16(wg) KEEP16(wo)

        if (tid < Hn / 2) hb[0][tid] = pkh(0.f, 0.f);
        __syncthreads();

        const float mI = (kq4 == 0) ? 1.f : 0.f;
        const float mF = (kq4 == 1) ? 1.f : 0.f;
        const float mG = (kq4 == 2) ? 1.f : 0.f;
        const float mO = (kq4 == 3) ? 1.f : 0.f;

        const h4* qq = (const h4*)pre0 + (size_t)(b * 128) * Gn + kq4 * Hn + u;
        _Float16* hs0b = hs0 + (size_t)b * Tn * Hn;

        h4 q0 = qq[0];
        h4 q1 = qq[Gn];
        const h4* pld = qq + 2 * (size_t)Gn;

        float cr = 0.f;

        auto tick = [&](int t, float pv) {
            const h2* hrow = &hb[t & 1][kq4 * 16];
            half8 hA = LD8H(hrow);     half8 hB = LD8H(hrow + 4);
            half8 hC = LD8H(hrow + 8); half8 hD = LD8H(hrow + 12);
            EXTRACT16(hv, hA, hB, hC, hD)

            float aI = 0.f, aF = 0.f, aG = 0.f, aO = 0.f;
            DOT4V(0)  DOT4V(1)  DOT4V(2)  DOT4V(3)
            DOT4V(4)  DOT4V(5)  DOT4V(6)  DOT4V(7)
            DOT4V(8)  DOT4V(9)  DOT4V(10) DOT4V(11)
            DOT4V(12) DOT4V(13) DOT4V(14) DOT4V(15)

            aI = fmaf(pv, mI, aI);
            aF = fmaf(pv, mF, aF);
            aG = fmaf(pv, mG, aG);
            aO = fmaf(pv, mO, aO);

            DPPADD(aI, 0xB1) DPPADD(aF, 0xB1) DPPADD(aG, 0xB1) DPPADD(aO, 0xB1)
            DPPADD(aI, 0x4E) DPPADD(aF, 0x4E) DPPADD(aG, 0x4E) DPPADD(aO, 0x4E)

            float iv = sigm(aI);
            float fv = sigm(aF);
            float gv = tanh_fast(aG);
            float ov = sigm(aO);
            cr = fv * cr + iv * gv;
            float hnew = ov * tanh_fast(cr);
            _Float16 hh = (_Float16)hnew;
            if (kq4 == 0) {
                ((_Float16*)hb[(t + 1) & 1])[u] = hh;
                hstage[(t >> 4) & 1][t & 15][u] = hh;
            }
            BAR_LDS();
        };

        auto flush_pub = [&](int ch) {
            if (tid < 256) {
                float4 v = ((const float4*)&hstage[ch & 1][0][0])[tid];
                *(float4*)(hs0b + (size_t)ch * 16 * Hn + tid * 8) = v;
            }
            asm volatile("s_waitcnt vmcnt(0)" ::: "memory");
            __syncthreads();
            if (tid == 0)
                __hip_atomic_store(flags0 + b, ch + 1, __ATOMIC_RELEASE,
                                   __HIP_MEMORY_SCOPE_AGENT);
        };

        for (int qr = 0; qr < 126; qr++) {
            tick(4 * qr,     (float)q0.x);
            tick(4 * qr + 1, (float)q0.y);
            tick(4 * qr + 2, (float)q0.z);
            tick(4 * qr + 3, (float)q0.w);
            if ((qr & 3) == 3) flush_pub(qr >> 2);
            q0 = q1;
            q1 = *pld; pld += Gn;
        }
        tick(504, (float)q0.x); tick(505, (float)q0.y);
        tick(506, (float)q0.z); tick(507, (float)q0.w);
        q0 = q1;
        tick(508, (float)q0.x); tick(509, (float)q0.y);
        tick(510, (float)q0.z); tick(511, (float)q0.w);
        flush_pub(31);

        // =================== PHASE B: consume layer 2 ====================
        __syncthreads();
        consumer_phase(b, tid, lane, kq4, u,
                       hs1 + (size_t)b * Tn * Hn,
                       hs2 + (size_t)b * Tn * Hn,
                       w_hh + 2 * (size_t)Gn * Hn,
                       wih_rest + (size_t)Gn * Hn,
                       b_ih + 2 * Gn, b_hh + 2 * Gn,
                       flags1, nullptr,
                       &hb[0][0], &hstage[0][0][0], &pL[0][0][0]);
    } else {
        // ==================== layer-1 consumer ===========================
        consumer_phase(b, tid, lane, kq4, u,
                       hs0 + (size_t)b * Tn * Hn,
                       hs1 + (size_t)b * Tn * Hn,
                       w_hh + (size_t)Gn * Hn,
                       wih_rest,
                       b_ih + Gn, b_hh + Gn,
                       flags0, flags1,
                       &hb[0][0], &hstage[0][0][0], &pL[0][0][0]);
    }
}

// ---------------------------------------------------------------------------
// Attention pooling + MLP head (reads fp16 hs). One block per batch item.
// ---------------------------------------------------------------------------
__global__ __launch_bounds__(256) void head_kernel(
    const _Float16* __restrict__ hs16,
    const float* __restrict__ w_attn, const float* __restrict__ b_attn,
    const float* __restrict__ w1, const float* __restrict__ b1,
    const float* __restrict__ w2, const float* __restrict__ b2,
    float* __restrict__ out)
{
    const int b = blockIdx.x;
    const int tid = threadIdx.x;
    __shared__ h2 wa2[Hn / 2];
    __shared__ __align__(16) float sc[Tn];
    __shared__ __align__(16) float red[256];
    __shared__ __align__(16) float ctx_sh[Hn];
    __shared__ __align__(16) float h1_sh[64];

    if (tid < Hn / 2) wa2[tid] = pkh(w_attn[2 * tid], w_attn[2 * tid + 1]);
    __syncthreads();

    const _Float16* hb = hs16 + (size_t)b * Tn * Hn;

    for (int t = tid; t < Tn; t += 256) {
        const h2* hp = (const h2*)(hb + (size_t)t * Hn);
        float s = 0.f;
        #pragma unroll
        for (int k = 0; k < 64; k++) s = dot2(hp[k], wa2[k], s);
        sc[t] = s + b_attn[0];
    }
    __syncthreads();

    float m = fmaxf(sc[tid], sc[tid + 256]);
    red[tid] = m; __syncthreads();
    for (int s_ = 128; s_ > 0; s_ >>= 1) {
        if (tid < s_) red[tid] = fmaxf(red[tid], red[tid + s_]);
        __syncthreads();
    }
    float mx = red[0];
    __syncthreads();
    float e0 = __expf(sc[tid] - mx), e1 = __expf(sc[tid + 256] - mx);
    sc[tid] = e0; sc[tid + 256] = e1;
    red[tid] = e0 + e1; __syncthreads();
    for (int s_ = 128; s_ > 0; s_ >>= 1) {
        if (tid < s_) red[tid] += red[tid + s_];
        __syncthreads();
    }
    float inv = 1.f / red[0];
    __syncthreads();

    {
        int jj = tid & 127, half = tid >> 7;
        float a = 0.f;
        for (int t = half * 256; t < half * 256 + 256; t++)
            a += sc[t] * (float)hb[(size_t)t * Hn + jj];
        red[tid] = a;
        __syncthreads();
        if (tid < Hn) ctx_sh[tid] = (red[tid] + red[tid + Hn]) * inv;
        __syncthreads();
    }

    if (tid < 64) {
        const float4* wvv = (const float4*)(w1 + (size_t)tid * Hn);
        const float4* cv = (const float4*)ctx_sh;
        float s = 0.f;
        #pragma unroll
        for (int k = 0; k < 32; k++) {
            float4 a = wvv[k], c = cv[k];
            s += a.x * c.x + a.y * c.y + a.z * c.z + a.w * c.w;
        }
        h1_sh[tid] = fmaxf(s + b1[tid], 0.f);
    }
    __syncthreads();

    if (tid < 4) {
        float s = 0.f;
        const float* wvv = w2 + tid * 64;
        #pragma unroll
        for (int k = 0; k < 64; k++) s += wvv[k] * h1_sh[k];
        out[b * 4 + tid] = s + b2[tid];
    }
}

// ---------------------------------------------------------------------------
extern "C" void kernel_launch(void* const* d_in, const int* in_sizes, int n_in,
                              void* d_out, int out_size, void* d_ws, size_t ws_size,
                              hipStream_t stream)
{
    const float* x        = (const float*)d_in[0];
    const float* w_ih0    = (const float*)d_in[1];
    const float* w_ih_rest= (const float*)d_in[2];
    const float* w_hh     = (const float*)d_in[3];
    const float* b_ih     = (const float*)d_in[4];
    const float* b_hh     = (const float*)d_in[5];
    const float* w_attn   = (const float*)d_in[6];
    const float* b_attn   = (const float*)d_in[7];
    const float* w1       = (const float*)d_in[8];
    const float* b1       = (const float*)d_in[9];
    const float* w2       = (const float*)d_in[10];
    const float* b2       = (const float*)d_in[11];
    float* out = (float*)d_out;

    const size_t nHS  = (size_t)Bn * Tn * Hn;       // 8,388,608
    const size_t nPRE = (size_t)Bn * Tn * Gn;       // 33,554,432 (fp16)

    _Float16* preh = (_Float16*)d_ws;
    _Float16* hs0  = preh + nPRE;
    _Float16* hs1  = hs0 + nHS;
    _Float16* hs2  = hs1 + nHS;
    int* flags0    = (int*)(hs2 + nHS);   // [128]
    int* flags1    = flags0 + Bn;         // [128]
    // total ~117 MB

    hipMemsetAsync(flags0, 0, 2 * Bn * sizeof(int), stream);

    // layer-0 pre-GEMM (x fp32 converted inline)
    gemm_pre<float><<<dim3(Bn * Tn / 64, 8), 256, 0, stream>>>(
        x, Dn, Tn * Dn, 0, 9, w_ih0, b_ih, b_hh, preh);

    // all three layers: cross-CU wavefront pipeline (256 CUs co-resident)
    pipe3<<<dim3(Bn, 2), 512, 0, stream>>>(preh, w_hh, w_ih_rest,
                                           b_ih, b_hh, hs0, hs1, hs2,
                                           flags0, flags1);

    head_kernel<<<Bn, 256, 0, stream>>>(hs2, w_attn, b_attn, w1, b1, w2, b2, out);
}